// Round 3
// baseline (179.889 us; speedup 1.0000x reference)
//
#include <hip/hip_runtime.h>

typedef float f4 __attribute__((ext_vector_type(4)));
typedef float f2 __attribute__((ext_vector_type(2)));

#define NPIX (32*512*512)        // 8388608
#define BN_EPS 1e-5f

// ws float layout:
// [0..5]   M1 sums of s_i
// [6..26]  M2 sums of s_i*s_j (upper tri, idx = 6 + a*(11-a)/2 + b, a<=b)
// [27]     S1 (sum o_pre), [28] S2 (sum o_pre^2)
// [29]     a2, [30] c2
// [32..332)  wpackD[25][12] = {a1w0..a1w5, beff, beff, w2c, w2c, 0, 0}
// [400..]  zbuf (zero region; accessed at [-1..4] -> floats 399..404)
// memset clears first 2048 bytes (floats 0..511) each launch.

__device__ __forceinline__ void stencil4(const float* __restrict__ x,
                                         const float* zbuf,
                                         int p, f4* s) {
    int rem = p & (512*512 - 1);
    int i = rem >> 9, jj = rem & 511;           // jj multiple of 4
    const float* xc = x + p;
    const float* xn = (i > 0)   ? xc - 512 : zbuf;
    const float* xs = (i < 511) ? xc + 512 : zbuf;
    f4 C = *(const f4*)xc;
    f4 N = *(const f4*)xn;
    f4 S = *(const f4*)xs;
    bool hw = (jj > 0), he = (jj < 508);
    float wv  = xc[hw ? -1 : 0]; wv  = hw ? wv  : 0.f;
    float ev  = xc[he ?  4 : 3]; ev  = he ? ev  : 0.f;
    float nwv = xn[hw ? -1 : 0]; nwv = hw ? nwv : 0.f;
    float sev = xs[he ?  4 : 3]; sev = he ? sev : 0.f;
    f4 E   = {C.y, C.z, C.w, ev};
    f4 W   = {wv,  C.x, C.y, C.z};
    f4 Ssh = {S.y, S.z, S.w, sev};
    f4 Nsh = {nwv, N.x, N.y, N.z};
    s[0] = C;
    s[1] = (S - N) * 0.5f;
    s[2] = (E - W) * 0.5f;
    s[3] = S + N - 2.f*C;
    s[4] = E + W - 2.f*C;
    s[5] = Ssh + Nsh - S - E;
}

__global__ __launch_bounds__(256) void k_moments(const float* __restrict__ x,
                                                 float* ws) {
    const float* zbuf = ws + 400;
    int t = threadIdx.x;
    int gbase = blockIdx.x * 1024 + t;          // float4-group index
    float acc[27];
    #pragma unroll
    for (int i = 0; i < 27; ++i) acc[i] = 0.f;
    #pragma unroll
    for (int k = 0; k < 4; ++k) {
        f4 s[6];
        stencil4(x, zbuf, (gbase + 256*k) * 4, s);
        #pragma unroll
        for (int a = 0; a < 6; ++a) {
            acc[a] += (s[a].x + s[a].y) + (s[a].z + s[a].w);
            #pragma unroll
            for (int b = a; b < 6; ++b) {
                int idx = 6 + a*(11-a)/2 + b;
                float v = acc[idx];
                v = fmaf(s[a].x, s[b].x, v);
                v = fmaf(s[a].y, s[b].y, v);
                v = fmaf(s[a].z, s[b].z, v);
                v = fmaf(s[a].w, s[b].w, v);
                acc[idx] = v;
            }
        }
    }
    #pragma unroll
    for (int i = 0; i < 27; ++i) {
        float v = acc[i];
        for (int off = 32; off; off >>= 1) v += __shfl_xor(v, off);
        acc[i] = v;
    }
    __shared__ float red[27][4];
    int wave = t >> 6, lane = t & 63;
    if (lane == 0)
        for (int i = 0; i < 27; ++i) red[i][wave] = acc[i];
    __syncthreads();
    if (t < 27) atomicAdd(&ws[t], red[t][0] + red[t][1] + red[t][2] + red[t][3]);
}

__global__ void k_stats1(const float* w1, const float* b1, const float* g1,
                         const float* beta1, const float* w2, float* ws) {
    int c = threadIdx.x;
    if (c >= 25) return;
    const float invN = 1.f / (float)NPIX;
    float m1[6], wr[6];
    #pragma unroll
    for (int i = 0; i < 6; ++i) m1[i] = ws[i] * invN;
    #pragma unroll
    for (int i = 0; i < 6; ++i) wr[i] = w1[c*6 + i];
    float bc = b1[c];
    float mean = bc;
    #pragma unroll
    for (int i = 0; i < 6; ++i) mean = fmaf(wr[i], m1[i], mean);
    float e2 = bc * bc;
    #pragma unroll
    for (int i = 0; i < 6; ++i) e2 = fmaf(2.f*bc*wr[i], m1[i], e2);
    #pragma unroll
    for (int i = 0; i < 6; ++i)
        #pragma unroll
        for (int j = 0; j < 6; ++j) {
            int a = i < j ? i : j, b = i < j ? j : i;
            float m2 = ws[6 + a*(11-a)/2 + b] * invN;
            e2 = fmaf(wr[i]*wr[j], m2, e2);
        }
    float var = e2 - mean*mean;
    float a1 = g1[c] * rsqrtf(var + BN_EPS);
    float* wp = ws + 32 + c*12;
    #pragma unroll
    for (int i = 0; i < 6; ++i) wp[i] = a1 * wr[i];
    float be = fmaf(a1, bc - mean, beta1[c]);
    wp[6] = be; wp[7] = be;
    wp[8] = w2[c]; wp[9] = w2[c];
    wp[10] = 0.f; wp[11] = 0.f;
}

__global__ __launch_bounds__(256) void k_main(const float* __restrict__ x,
                                              float* ws,
                                              const float* b2,
                                              float* __restrict__ opre) {
    __shared__ float lw[25*12];
    int t = threadIdx.x;
    if (t < 75) ((f4*)lw)[t] = ((const f4*)(ws + 32))[t];
    const float* zbuf = ws + 400;
    int g0 = blockIdx.x * 512 + t;              // first float4-group

    f2 sp[6][4];
    {
        f4 s[6];
        stencil4(x, zbuf, g0 * 4, s);
        #pragma unroll
        for (int a = 0; a < 6; ++a) { sp[a][0] = s[a].xy; sp[a][1] = s[a].zw; }
        stencil4(x, zbuf, (g0 + 256) * 4, s);
        #pragma unroll
        for (int a = 0; a < 6; ++a) { sp[a][2] = s[a].xy; sp[a][3] = s[a].zw; }
    }
    __syncthreads();

    float b2v = b2[0];
    f2 o[4];
    #pragma unroll
    for (int q = 0; q < 4; ++q) o[q] = (f2){b2v, b2v};

    #pragma unroll
    for (int c = 0; c < 25; ++c) {
        f4 A = *(const f4*)&lw[c*12];       // w0 w1 w2 w3
        f4 B = *(const f4*)&lw[c*12 + 4];   // w4 w5 beff beff
        f2 Wc = *(const f2*)&lw[c*12 + 8];  // w2c w2c
        f2 w01 = A.xy, w23 = A.zw, w45 = B.xy, be2 = B.zw;
        #pragma unroll
        for (int q = 0; q < 4; ++q) {
            f2 tt;
            asm("v_pk_fma_f32 %0, %1, %2, %3 op_sel:[0,0,0] op_sel_hi:[0,1,1]"
                : "=v"(tt) : "v"(w01), "v"(sp[0][q]), "v"(be2));
            asm("v_pk_fma_f32 %0, %1, %2, %0 op_sel:[1,0,0] op_sel_hi:[1,1,1]"
                : "+v"(tt) : "v"(w01), "v"(sp[1][q]));
            asm("v_pk_fma_f32 %0, %1, %2, %0 op_sel:[0,0,0] op_sel_hi:[0,1,1]"
                : "+v"(tt) : "v"(w23), "v"(sp[2][q]));
            asm("v_pk_fma_f32 %0, %1, %2, %0 op_sel:[1,0,0] op_sel_hi:[1,1,1]"
                : "+v"(tt) : "v"(w23), "v"(sp[3][q]));
            asm("v_pk_fma_f32 %0, %1, %2, %0 op_sel:[0,0,0] op_sel_hi:[0,1,1]"
                : "+v"(tt) : "v"(w45), "v"(sp[4][q]));
            asm("v_pk_fma_f32 %0, %1, %2, %0 op_sel:[1,0,0] op_sel_hi:[1,1,1]"
                : "+v"(tt) : "v"(w45), "v"(sp[5][q]));
            tt.x = fmaxf(tt.x, 0.f);
            tt.y = fmaxf(tt.y, 0.f);
            asm("v_pk_fma_f32 %0, %1, %2, %0"
                : "+v"(o[q]) : "v"(Wc), "v"(tt));
        }
    }

    f4 O0 = {o[0].x, o[0].y, o[1].x, o[1].y};
    f4 O1 = {o[2].x, o[2].y, o[3].x, o[3].y};
    *(f4*)(opre + g0*4) = O0;
    *(f4*)(opre + (g0 + 256)*4) = O1;

    float l1 = (O0.x + O0.y) + (O0.z + O0.w) + (O1.x + O1.y) + (O1.z + O1.w);
    float l2 = 0.f;
    l2 = fmaf(O0.x, O0.x, l2); l2 = fmaf(O0.y, O0.y, l2);
    l2 = fmaf(O0.z, O0.z, l2); l2 = fmaf(O0.w, O0.w, l2);
    l2 = fmaf(O1.x, O1.x, l2); l2 = fmaf(O1.y, O1.y, l2);
    l2 = fmaf(O1.z, O1.z, l2); l2 = fmaf(O1.w, O1.w, l2);
    for (int off = 32; off; off >>= 1) { l1 += __shfl_xor(l1, off); l2 += __shfl_xor(l2, off); }
    __shared__ float red[2][4];
    int wave = t >> 6, lane = t & 63;
    if (lane == 0) { red[0][wave] = l1; red[1][wave] = l2; }
    __syncthreads();
    if (t == 0) atomicAdd(&ws[27], red[0][0]+red[0][1]+red[0][2]+red[0][3]);
    if (t == 1) atomicAdd(&ws[28], red[1][0]+red[1][1]+red[1][2]+red[1][3]);
}

__global__ void k_stats2(const float* g2, const float* beta2, float* ws) {
    const float invN = 1.f / (float)NPIX;
    float mean = ws[27] * invN;
    float var  = ws[28] * invN - mean*mean;
    float a2 = g2[0] * rsqrtf(var + BN_EPS);
    ws[29] = a2;
    ws[30] = fmaf(-mean, a2, beta2[0]);
}

__global__ __launch_bounds__(256) void k_final(const float* __restrict__ x,
                                               const float* ws,
                                               float* out) {
    int idx = blockIdx.x * 256 + threadIdx.x;   // float4 index
    float a2 = ws[29], c2 = ws[30];
    f4 o  = ((const f4*)out)[idx];
    f4 xv = ((const f4*)x)[idx];
    f4 r;
    r.x = fmaxf(fmaf(a2, o.x, c2), 0.f) + xv.x;
    r.y = fmaxf(fmaf(a2, o.y, c2), 0.f) + xv.y;
    r.z = fmaxf(fmaf(a2, o.z, c2), 0.f) + xv.z;
    r.w = fmaxf(fmaf(a2, o.w, c2), 0.f) + xv.w;
    ((f4*)out)[idx] = r;
}

extern "C" void kernel_launch(void* const* d_in, const int* in_sizes, int n_in,
                              void* d_out, int out_size, void* d_ws, size_t ws_size,
                              hipStream_t stream) {
    const float* x     = (const float*)d_in[0];
    const float* w1    = (const float*)d_in[1];
    const float* b1    = (const float*)d_in[2];
    const float* g1    = (const float*)d_in[3];
    const float* beta1 = (const float*)d_in[4];
    const float* w2    = (const float*)d_in[5];
    const float* b2    = (const float*)d_in[6];
    const float* g2    = (const float*)d_in[7];
    const float* beta2 = (const float*)d_in[8];
    float* out = (float*)d_out;
    float* ws  = (float*)d_ws;

    hipMemsetAsync(ws, 0, 2048, stream);
    k_moments<<<2048, 256, 0, stream>>>(x, ws);
    k_stats1 <<<1, 32, 0, stream>>>(w1, b1, g1, beta1, w2, ws);
    k_main   <<<4096, 256, 0, stream>>>(x, ws, b2, out);
    k_stats2 <<<1, 1, 0, stream>>>(g2, beta2, ws);
    k_final  <<<8192, 256, 0, stream>>>(x, ws, out);
}